// Round 1
// 541.423 us; speedup vs baseline: 1.2159x; 1.2159x over previous
//
#include <hip/hip_runtime.h>
#include <stdint.h>

#define NB  64
#define SEQ 2048
#define DIM 512
#define NS  (NB*SEQ)   // 131072 flattened s-rows

typedef __bf16 bf16x8 __attribute__((ext_vector_type(8)));
typedef float  f32x4  __attribute__((ext_vector_type(4)));
typedef unsigned int u32;
typedef unsigned short u16;
typedef unsigned int u32x2 __attribute__((ext_vector_type(2)));
typedef unsigned int u32x4 __attribute__((ext_vector_type(4)));

// pack two fp32 -> two bf16 (round-half-up; same numerics as verified kernel)
__device__ __forceinline__ u32 pk_bf16(float a, float b){
  union {float f; u32 i;} x, y; x.f = a; y.f = b;
  return ((x.i + 0x8000u) >> 16) | ((y.i + 0x8000u) & 0xffff0000u);
}
// tanh(x) = 1 - 2/(e^{2x}+1)
__device__ __forceinline__ float fast_tanh(float x){
  float e = __builtin_amdgcn_exp2f(x * 2.885390081777927f);  // 2*log2(e)
  return 1.0f - 2.0f*__builtin_amdgcn_rcpf(e + 1.0f);
}
// async 16B global -> LDS (per-lane gptr; LDS dest = wave-uniform base + lane*16,
// we pass per-lane ptr that equals exactly that)
__device__ __forceinline__ void gload_lds16(const void* g, void* l){
  __builtin_amdgcn_global_load_lds((const __attribute__((address_space(1))) void*)g,
                                   (__attribute__((address_space(3))) void*)l, 16, 0, 0);
}

// ---------------- kernel 0: Wr_w fp32 -> bf16 (L2-resident operand) ---------
__global__ void wconv_kernel(const float* __restrict__ Wr_w, u16* __restrict__ wrbf)
{
  const int i = blockIdx.x*256 + threadIdx.x;        // 65536 chunks of 4 floats
  f32x4 v = ((const f32x4*)Wr_w)[i];
  u32x2 p; p.x = pk_bf16(v.x, v.y); p.y = pk_bf16(v.z, v.w);
  ((u32x2*)wrbf)[i] = p;
}

// ---------------- kernel 1: q = query @ Wq_w^T + Wq_b (fp32 into ws) --------
__global__ void q_kernel(const float* __restrict__ query, const float* __restrict__ Wq_w,
                         const float* __restrict__ Wq_b, float* __restrict__ qws)
{
  __shared__ float lq[DIM];
  const int b   = blockIdx.x;
  const int tid = threadIdx.x;           // 256
  const int e   = blockIdx.y*256 + tid;  // 0..511
  for (int i = tid; i < DIM; i += 256) lq[i] = query[b*DIM + i];
  __syncthreads();
  const float* wr = Wq_w + (size_t)e*DIM;
  float acc = 0.f;
  for (int d = 0; d < DIM; d += 4){
    f32x4 w = *(const f32x4*)(wr + d);
    acc += w.x*lq[d] + w.y*lq[d+1] + w.z*lq[d+2] + w.w*lq[d+3];
  }
  qws[b*DIM + e] = acc + Wq_b[e];
}

// ---------------- kernel 2: one block = 64 s-rows x ALL 512 e ---------------
// ref tile staged ONCE (bf16, swizzled, 64KB).  Wr streamed via global_load_lds
// into 2x8KB double buffer (BK=32 chunks, 4 e-tiles of 128).  Epilogue per
// e-tile: bias + transposed-out stores + in-register logits accumulation.
// LDS = 80KB exactly -> 2 blocks/CU.
#define BN 64
#define ET 128
#define BK 32

__global__ __launch_bounds__(256)
void main_kernel(const float* __restrict__ ref,  const u16* __restrict__ wrbf,
                 const float* __restrict__ Wr_b, const float* __restrict__ value,
                 const float* __restrict__ qws,  float* __restrict__ out)
{
  __shared__ __align__(16) char smem[81920];
  char* refL = smem;                      // [64][512] bf16, 1024B rows, chunk^=(row&7)
  char* wb0  = smem + 65536;              // [128][32] bf16, linear 64B rows
  char* wb1  = smem + 65536 + 8192;

  const int tid  = threadIdx.x;
  const int lane = tid & 63, wave = tid >> 6;
  const int col  = lane & 15, quad = lane >> 4;
  const size_t s0 = (size_t)blockIdx.x * BN;
  const int b  = (int)(s0 >> 11);         // 2048 % 64 == 0: tile within one batch
  const int sb = (int)(s0 & 2047);

  auto stage_w = [&](char* dst, int c){   // chunk c: et = c>>4, kt = c&15
    const int et = c >> 4, kt = c & 15;
#pragma unroll
    for (int j = 0; j < 2; ++j){
      const int idx = j*256 + wave*64 + lane;          // 0..511 (16B units)
      const int er  = et*ET + (idx >> 2);
      const u16* g  = wrbf + (size_t)er*DIM + kt*BK + (idx & 3)*8;
      gload_lds16(g, dst + (size_t)idx*16);
    }
  };

  // issue first Wr chunk, then stage ref tile (latencies overlap)
  stage_w(wb0, 0);

  for (int it = 0; it < 16; ++it){
    const int c   = it*256 + tid;          // 4096 16B-chunks: [64 rows][64 chunks]
    const int row = c >> 6, ch = c & 63;
    const float* g = ref + (s0 + row)*DIM + ch*8;
    f32x4 x0 = *(const f32x4*)g, x1 = *(const f32x4*)(g+4);
    u32x4 p;
    p[0]=pk_bf16(x0.x,x0.y); p[1]=pk_bf16(x0.z,x0.w);
    p[2]=pk_bf16(x1.x,x1.y); p[3]=pk_bf16(x1.z,x1.w);
    *(u32x4*)(refL + row*1024 + ((ch ^ (row&7)))*16) = p;
  }
  __syncthreads();                         // drains ds_writes AND chunk-0 vmcnt

  f32x4 acc[2][4];
#pragma unroll
  for (int mi = 0; mi < 2; ++mi)
#pragma unroll
    for (int ni = 0; ni < 4; ++ni) acc[mi][ni] = (f32x4)0.0f;
  float lsum[4] = {0.f, 0.f, 0.f, 0.f};

  char* wcur = wb0;
  char* wnxt = wb1;

  for (int c = 0; c < 64; ++c){
    if (c + 1 < 64) stage_w(wnxt, c + 1);  // prefetch next chunk (1-deep)

    const int kt = c & 15;
    bf16x8 af[2], bfr[4];
#pragma unroll
    for (int mi = 0; mi < 2; ++mi)         // A rows: wave's 32 e-rows
      af[mi] = *(const bf16x8*)(wcur + (wave*32 + mi*16 + col)*64 + quad*16);
#pragma unroll
    for (int ni = 0; ni < 4; ++ni){        // B rows: all 64 s-rows, swizzled
      const int r = ni*16 + col;
      bfr[ni] = *(const bf16x8*)(refL + r*1024 + (((kt*4 + quad) ^ (r&7)))*16);
    }
#pragma unroll
    for (int mi = 0; mi < 2; ++mi)
#pragma unroll
      for (int ni = 0; ni < 4; ++ni)
        acc[mi][ni] = __builtin_amdgcn_mfma_f32_16x16x32_bf16(af[mi], bfr[ni], acc[mi][ni], 0, 0, 0);

    if (kt == 15){                         // e-tile finished: fused epilogue
      const int et = c >> 4;
#pragma unroll
      for (int mi = 0; mi < 2; ++mi){
#pragma unroll
        for (int rg = 0; rg < 4; ++rg){
          const int eg = et*ET + wave*32 + mi*16 + quad*4 + rg;  // C row = e
          const float bias = Wr_b[eg];
          const float qe   = qws[b*DIM + eg];
          const float val  = value[eg];
          float* orow = out + ((size_t)(b*DIM + eg))*SEQ + sb;
#pragma unroll
          for (int ni = 0; ni < 4; ++ni){  // C col = s (lane&15): 64B segments
            const float r = acc[mi][ni][rg] + bias;
            orow[ni*16 + col] = r;
            lsum[ni] += fast_tanh(qe + r) * val;
          }
        }
      }
#pragma unroll
      for (int mi = 0; mi < 2; ++mi)
#pragma unroll
        for (int ni = 0; ni < 4; ++ni) acc[mi][ni] = (f32x4)0.0f;
    }

    __syncthreads();                       // vmcnt(0)+lgkmcnt(0): next chunk ready
    char* t = wcur; wcur = wnxt; wnxt = t;
  }

  // logits: quad-reduce (e within wave) then cross-wave via LDS, single write
#pragma unroll
  for (int ni = 0; ni < 4; ++ni){
    lsum[ni] += __shfl_xor(lsum[ni], 16);
    lsum[ni] += __shfl_xor(lsum[ni], 32);
  }
  float* lred = (float*)(smem + 65536);    // reuse Wr buffers (all consumed)
  if (quad == 0){
#pragma unroll
    for (int ni = 0; ni < 4; ++ni) lred[wave*64 + ni*16 + col] = lsum[ni];
  }
  __syncthreads();
  if (tid < BN){
    const float s = lred[tid] + lred[64+tid] + lred[128+tid] + lred[192+tid];
    out[(size_t)NB*DIM*SEQ + b*SEQ + sb + tid] = 10.0f * fast_tanh(s);
  }
}

extern "C" void kernel_launch(void* const* d_in, const int* in_sizes, int n_in,
                              void* d_out, int out_size, void* d_ws, size_t ws_size,
                              hipStream_t stream)
{
  const float* query = (const float*)d_in[0];
  const float* ref   = (const float*)d_in[1];
  const float* Wq_w  = (const float*)d_in[2];
  const float* Wq_b  = (const float*)d_in[3];
  const float* Wr_w  = (const float*)d_in[4];
  const float* Wr_b  = (const float*)d_in[5];
  const float* value = (const float*)d_in[6];
  float* out = (float*)d_out;

  float* qws  = (float*)d_ws;                       // 64*512 fp32 = 128 KB
  u16*   wrbf = (u16*)((float*)d_ws + NB*DIM);      // 512*512 bf16 = 512 KB

  wconv_kernel<<<dim3(256), dim3(256), 0, stream>>>(Wr_w, wrbf);
  q_kernel<<<dim3(NB, 2), dim3(256), 0, stream>>>(query, Wq_w, Wq_b, qws);
  main_kernel<<<dim3(NS/BN), dim3(256), 0, stream>>>(ref, wrbf, Wr_b, value, qws, out);
}

// Round 2
// 534.778 us; speedup vs baseline: 1.2310x; 1.0124x over previous
//
#include <hip/hip_runtime.h>
#include <stdint.h>

#define NB  64
#define SEQ 2048
#define DIM 512
#define NS  (NB*SEQ)   // 131072 flattened s-rows

typedef __bf16 bf16x8 __attribute__((ext_vector_type(8)));
typedef float  f32x4  __attribute__((ext_vector_type(4)));
typedef unsigned int u32;
typedef unsigned short u16;
typedef unsigned int u32x4 __attribute__((ext_vector_type(4)));

// pack two fp32 -> two bf16 (round-half-up; same numerics as verified kernel)
__device__ __forceinline__ u32 pk_bf16(float a, float b){
  union {float f; u32 i;} x, y; x.f = a; y.f = b;
  return ((x.i + 0x8000u) >> 16) | ((y.i + 0x8000u) & 0xffff0000u);
}
// tanh(x) = 1 - 2/(e^{2x}+1)
__device__ __forceinline__ float fast_tanh(float x){
  float e = __builtin_amdgcn_exp2f(x * 2.885390081777927f);  // 2*log2(e)
  return 1.0f - 2.0f*__builtin_amdgcn_rcpf(e + 1.0f);
}

// ---------------- kernel 0: Wr_w fp32 -> bf16 fragment-image ---------------
// cell i in [0,32768): eb=i>>10, kt=(i>>6)&15, quad=(i>>4)&3, col=i&15.
// cell holds Wr_w[e = eb*16+col][k = kt*32+quad*8 .. +7] as 8 bf16 (16 B).
// A wave's B-fragment load for (eb,kt) then reads 64 lanes x 16 B CONTIGUOUS.
__global__ void wconv_kernel(const float* __restrict__ Wr_w, u16* __restrict__ wrbf)
{
  const int i = blockIdx.x*256 + threadIdx.x;        // 32768 cells
  const int eb = i >> 10, kt = (i >> 6) & 15, quad = (i >> 4) & 3, col = i & 15;
  const float* g = Wr_w + (size_t)(eb*16 + col)*DIM + kt*32 + quad*8;
  f32x4 a = *(const f32x4*)g, c = *(const f32x4*)(g + 4);
  u32x4 p;
  p[0]=pk_bf16(a.x,a.y); p[1]=pk_bf16(a.z,a.w);
  p[2]=pk_bf16(c.x,c.y); p[3]=pk_bf16(c.z,c.w);
  ((u32x4*)wrbf)[i] = p;
}

// ---------------- kernel 1: q = query @ Wq_w^T + Wq_b (fp32 into ws) --------
__global__ void q_kernel(const float* __restrict__ query, const float* __restrict__ Wq_w,
                         const float* __restrict__ Wq_b, float* __restrict__ qws)
{
  __shared__ float lq[DIM];
  const int b   = blockIdx.x;
  const int tid = threadIdx.x;           // 256
  const int e   = blockIdx.y*256 + tid;  // 0..511
  for (int i = tid; i < DIM; i += 256) lq[i] = query[b*DIM + i];
  __syncthreads();
  const float* wr = Wq_w + (size_t)e*DIM;
  float acc = 0.f;
  for (int d = 0; d < DIM; d += 4){
    f32x4 w = *(const f32x4*)(wr + d);
    acc += w.x*lq[d] + w.y*lq[d+1] + w.z*lq[d+2] + w.w*lq[d+3];
  }
  qws[b*DIM + e] = acc + Wq_b[e];
}

// ---------------- kernel 2: one block = 64 s-rows x ALL 512 e ---------------
// ref tile staged ONCE into swizzled LDS (64 KB). Wr fragments loaded straight
// from L2-resident wrbf into registers (double-buffered) -> the 64-step k-loop
// has ZERO barriers; waves free-run. kt-outer/et-inner: 4 ref frags per kt
// reused across 4 e-tiles. Swapped MFMA operands -> D[s][e]: lane holds 4
// consecutive s -> coalesced f32x4 stores in a single post-loop epilogue.
#define BN 64

__global__ __launch_bounds__(256, 2)
void main_kernel(const float* __restrict__ ref,  const u16* __restrict__ wrbf,
                 const float* __restrict__ Wr_b, const float* __restrict__ value,
                 const float* __restrict__ qws,  float* __restrict__ out)
{
  __shared__ __align__(16) char smem[66560];
  char*  refL = smem;                     // [64 rows][1024 B], chunk^(row&7)
  float* lred = (float*)(smem + 65536);   // [4][64] logits partials

  const int tid  = threadIdx.x;
  const int lane = tid & 63, wave = tid >> 6;
  const int col  = lane & 15, quad = lane >> 4;
  const size_t s0 = (size_t)blockIdx.x * BN;
  const int b  = (int)(s0 >> 11);         // 2048 % 64 == 0: tile within one batch
  const int sb = (int)(s0 & 2047);

  // ---- stage ref tile -> bf16 swizzled LDS (the only barrier-protected phase)
#pragma unroll 4
  for (int it = 0; it < 16; ++it){
    const int c   = it*256 + tid;          // 4096 16B-chunks: [64 rows][64 chunks]
    const int row = c >> 6, ch = c & 63;
    const float* g = ref + (s0 + row)*DIM + ch*8;
    f32x4 x0 = *(const f32x4*)g, x1 = *(const f32x4*)(g+4);
    u32x4 p;
    p[0]=pk_bf16(x0.x,x0.y); p[1]=pk_bf16(x0.z,x0.w);
    p[2]=pk_bf16(x1.x,x1.y); p[3]=pk_bf16(x1.z,x1.w);
    *(u32x4*)(refL + row*1024 + (ch ^ (row&7))*16) = p;
  }
  __syncthreads();

  f32x4 acc[4][2][4];                      // [et][mi][ni] -- all statically indexed
#pragma unroll
  for (int et = 0; et < 4; ++et)
#pragma unroll
    for (int mi = 0; mi < 2; ++mi)
#pragma unroll
      for (int ni = 0; ni < 4; ++ni) acc[et][mi][ni] = (f32x4)0.0f;

  // W fragment pointer: contiguous 1 KB per (eb,kt), lane-indexed 16 B cells
  auto wptr = [&](int et, int mi, int kt){
    const int eb = et*8 + wave*2 + mi;     // e-block of 16
    return (const bf16x8*)(wrbf + ((size_t)((eb*16 + kt)*64 + lane))*8);
  };

  bf16x8 wbuf[2][2];                       // [parity][mi], register double-buffer
  wbuf[0][0] = *wptr(0, 0, 0);
  wbuf[0][1] = *wptr(0, 1, 0);
  bf16x8 rf[4];

  for (int kt = 0; kt < 16; ++kt){
#pragma unroll
    for (int ni = 0; ni < 4; ++ni){        // ref frags for this kt (reused 4x)
      const int r = ni*16 + col;
      rf[ni] = *(const bf16x8*)(refL + r*1024 + (((kt*4 + quad) ^ (r&7)))*16);
    }
#pragma unroll
    for (int et = 0; et < 4; ++et){
      const int p = et & 1;
      if (!(kt == 15 && et == 3)){         // prefetch next step's W frags
        const int ne = (et + 1) & 3, nk = (et == 3) ? kt + 1 : kt;
        wbuf[p^1][0] = *wptr(ne, 0, nk);
        wbuf[p^1][1] = *wptr(ne, 1, nk);
      }
#pragma unroll
      for (int mi = 0; mi < 2; ++mi)
#pragma unroll
        for (int ni = 0; ni < 4; ++ni)     // D[s][e]: swapped operands
          acc[et][mi][ni] = __builtin_amdgcn_mfma_f32_16x16x32_bf16(
                              rf[ni], wbuf[p][mi], acc[et][mi][ni], 0, 0, 0);
    }
  }

  // ---- epilogue: bias + coalesced f32x4 stores + fused logits --------------
  float ls[4][4];
#pragma unroll
  for (int ni = 0; ni < 4; ++ni)
#pragma unroll
    for (int rg = 0; rg < 4; ++rg) ls[ni][rg] = 0.f;

#pragma unroll
  for (int et = 0; et < 4; ++et){
#pragma unroll
    for (int mi = 0; mi < 2; ++mi){
      const int e = et*128 + wave*32 + mi*16 + col;   // lane's own e-row
      const float bb = Wr_b[e];
      const float qq = qws[b*DIM + e];
      const float vv = value[e];
      float* orow = out + ((size_t)(b*DIM + e))*SEQ + sb + quad*4;
#pragma unroll
      for (int ni = 0; ni < 4; ++ni){      // s = sb + ni*16 + quad*4 + rg
        f32x4 v = acc[et][mi][ni];
        v.x += bb; v.y += bb; v.z += bb; v.w += bb;
        *(f32x4*)(orow + ni*16) = v;       // 4 consecutive s: 16 B store
        ls[ni][0] += fast_tanh(qq + v.x) * vv;
        ls[ni][1] += fast_tanh(qq + v.y) * vv;
        ls[ni][2] += fast_tanh(qq + v.z) * vv;
        ls[ni][3] += fast_tanh(qq + v.w) * vv;
      }
    }
  }

  // logits: reduce over e = cols (shfl) then waves (LDS)
#pragma unroll
  for (int ni = 0; ni < 4; ++ni)
#pragma unroll
    for (int rg = 0; rg < 4; ++rg){
      float x = ls[ni][rg];
      x += __shfl_xor(x, 1); x += __shfl_xor(x, 2);
      x += __shfl_xor(x, 4); x += __shfl_xor(x, 8);
      ls[ni][rg] = x;
    }
  if (col == 0){
#pragma unroll
    for (int ni = 0; ni < 4; ++ni)
#pragma unroll
      for (int rg = 0; rg < 4; ++rg)
        lred[wave*64 + ni*16 + quad*4 + rg] = ls[ni][rg];
  }
  __syncthreads();
  if (tid < BN){
    const float s = lred[tid] + lred[64+tid] + lred[128+tid] + lred[192+tid];
    out[(size_t)NB*DIM*SEQ + b*SEQ + sb + tid] = 10.0f * fast_tanh(s);
  }
}

extern "C" void kernel_launch(void* const* d_in, const int* in_sizes, int n_in,
                              void* d_out, int out_size, void* d_ws, size_t ws_size,
                              hipStream_t stream)
{
  const float* query = (const float*)d_in[0];
  const float* ref   = (const float*)d_in[1];
  const float* Wq_w  = (const float*)d_in[2];
  const float* Wq_b  = (const float*)d_in[3];
  const float* Wr_w  = (const float*)d_in[4];
  const float* Wr_b  = (const float*)d_in[5];
  const float* value = (const float*)d_in[6];
  float* out = (float*)d_out;

  float* qws  = (float*)d_ws;                       // 64*512 fp32 = 128 KB
  u16*   wrbf = (u16*)((float*)d_ws + NB*DIM);      // 512*512 bf16 = 512 KB

  wconv_kernel<<<dim3(128), dim3(256), 0, stream>>>(Wr_w, wrbf);
  q_kernel<<<dim3(NB, 2), dim3(256), 0, stream>>>(query, Wq_w, Wq_b, qws);
  main_kernel<<<dim3(NS/BN), dim3(256), 0, stream>>>(ref, wrbf, Wr_b, value, qws, out);
}

// Round 3
// 522.386 us; speedup vs baseline: 1.2602x; 1.0237x over previous
//
#include <hip/hip_runtime.h>
#include <stdint.h>

#define NB  64
#define SEQ 2048
#define DIM 512
#define NS  (NB*SEQ)   // 131072 flattened s-rows

typedef __bf16 bf16x8 __attribute__((ext_vector_type(8)));
typedef float  f32x4  __attribute__((ext_vector_type(4)));
typedef unsigned int u32;
typedef unsigned short u16;
typedef unsigned int u32x4 __attribute__((ext_vector_type(4)));

// pack two fp32 -> two bf16 (round-half-up; same numerics as verified kernel)
__device__ __forceinline__ u32 pk_bf16(float a, float b){
  union {float f; u32 i;} x, y; x.f = a; y.f = b;
  return ((x.i + 0x8000u) >> 16) | ((y.i + 0x8000u) & 0xffff0000u);
}
// tanh(x) = 1 - 2/(e^{2x}+1)
__device__ __forceinline__ float fast_tanh(float x){
  float e = __builtin_amdgcn_exp2f(x * 2.885390081777927f);  // 2*log2(e)
  return 1.0f - 2.0f*__builtin_amdgcn_rcpf(e + 1.0f);
}

// ---------------- kernel 0: Wr_w fp32 -> bf16 fragment-image ---------------
// cell i in [0,32768): eb=i>>10, kt=(i>>6)&15, quad=(i>>4)&3, col=i&15.
// cell holds Wr_w[e = eb*16+col][k = kt*32+quad*8 .. +7] as 8 bf16 (16 B).
// A wave's B-fragment load for (eb,kt) then reads 64 lanes x 16 B CONTIGUOUS.
__global__ void wconv_kernel(const float* __restrict__ Wr_w, u16* __restrict__ wrbf)
{
  const int i = blockIdx.x*256 + threadIdx.x;        // 32768 cells
  const int eb = i >> 10, kt = (i >> 6) & 15, quad = (i >> 4) & 3, col = i & 15;
  const float* g = Wr_w + (size_t)(eb*16 + col)*DIM + kt*32 + quad*8;
  f32x4 a = *(const f32x4*)g, c = *(const f32x4*)(g + 4);
  u32x4 p;
  p[0]=pk_bf16(a.x,a.y); p[1]=pk_bf16(a.z,a.w);
  p[2]=pk_bf16(c.x,c.y); p[3]=pk_bf16(c.z,c.w);
  ((u32x4*)wrbf)[i] = p;
}

// ---------------- kernel 1: q = query @ Wq_w^T + Wq_b (fp32 into ws) --------
__global__ void q_kernel(const float* __restrict__ query, const float* __restrict__ Wq_w,
                         const float* __restrict__ Wq_b, float* __restrict__ qws)
{
  __shared__ float lq[DIM];
  const int b   = blockIdx.x;
  const int tid = threadIdx.x;           // 256
  const int e   = blockIdx.y*256 + tid;  // 0..511
  for (int i = tid; i < DIM; i += 256) lq[i] = query[b*DIM + i];
  __syncthreads();
  const float* wr = Wq_w + (size_t)e*DIM;
  float acc = 0.f;
  for (int d = 0; d < DIM; d += 4){
    f32x4 w = *(const f32x4*)(wr + d);
    acc += w.x*lq[d] + w.y*lq[d+1] + w.z*lq[d+2] + w.w*lq[d+3];
  }
  qws[b*DIM + e] = acc + Wq_b[e];
}

// ---------------- kernel 2: one block = 64 s-rows x ALL 512 e ---------------
// Two sequential e-half passes (256 e each) shrink the live accumulator to 64
// regs, buying a 2-kt-deep W prefetch ring (window = 32 MFMA, covers L2
// latency) + 1-kt ref ds_read prefetch + preloaded epilogue constants.
// ref tile staged ONCE (bf16, swizzled LDS); k-loop has ZERO barriers.
#define BN 64

__global__ __launch_bounds__(256, 2)
void main_kernel(const float* __restrict__ ref,  const u16* __restrict__ wrbf,
                 const float* __restrict__ Wr_b, const float* __restrict__ value,
                 const float* __restrict__ qws,  float* __restrict__ out)
{
  __shared__ __align__(16) char smem[66560];
  char*  refL = smem;                     // [64 rows][1024 B], chunk^(row&7)
  float* lred = (float*)(smem + 65536);   // [4][64] logits partials

  const int tid  = threadIdx.x;
  const int lane = tid & 63, wave = tid >> 6;
  const int col  = lane & 15, quad = lane >> 4;
  const size_t s0 = (size_t)blockIdx.x * BN;
  const int b  = (int)(s0 >> 11);         // 2048 % 64 == 0: tile within one batch
  const int sb = (int)(s0 & 2047);

  // W fragment for linear step K (0..31): eh=K>>4, kt=K&15, frag f=(et*2+mi)
  auto wptr = [&](int K, int f){
    const int eh = K >> 4, kt = K & 15;
    const int eb = eh*16 + (f>>1)*8 + wave*2 + (f&1);
    return (const bf16x8*)(wrbf + ((size_t)((eb*16 + kt)*64 + lane))*8);
  };

  bf16x8 wb[4][4];                        // ring [K&3][f], 2-kt lookahead
#pragma unroll
  for (int f = 0; f < 4; ++f) wb[0][f] = *wptr(0, f);

  // epilogue constants: e = eh*256 + et*128 + wave*32 + mi*16 + col
  float bb[8], qq[8], vv[8];
#pragma unroll
  for (int i = 0; i < 8; ++i){
    const int e = (i>>2)*256 + ((i>>1)&1)*128 + wave*32 + (i&1)*16 + col;
    bb[i] = Wr_b[e]; qq[i] = qws[b*DIM + e]; vv[i] = value[e];
  }

  // ---- stage ref tile -> bf16 swizzled LDS --------------------------------
#pragma unroll 4
  for (int it = 0; it < 16; ++it){
    const int c   = it*256 + tid;          // 4096 16B-chunks: [64 rows][64 chunks]
    const int row = c >> 6, ch = c & 63;
    const float* g = ref + (s0 + row)*DIM + ch*8;
    f32x4 x0 = *(const f32x4*)g, x1 = *(const f32x4*)(g+4);
    u32x4 p;
    p[0]=pk_bf16(x0.x,x0.y); p[1]=pk_bf16(x0.z,x0.w);
    p[2]=pk_bf16(x1.x,x1.y); p[3]=pk_bf16(x1.z,x1.w);
    *(u32x4*)(refL + row*1024 + (ch ^ (row&7))*16) = p;
  }
#pragma unroll
  for (int f = 0; f < 4; ++f) wb[1][f] = *wptr(1, f);
  __syncthreads();

  f32x4 acc[2][2][4];                      // per-pass accs: [et][mi][ni]
#pragma unroll
  for (int et = 0; et < 2; ++et)
#pragma unroll
    for (int mi = 0; mi < 2; ++mi)
#pragma unroll
      for (int ni = 0; ni < 4; ++ni) acc[et][mi][ni] = (f32x4)0.0f;
  float ls[4][4];
#pragma unroll
  for (int ni = 0; ni < 4; ++ni)
#pragma unroll
    for (int rg = 0; rg < 4; ++rg) ls[ni][rg] = 0.f;

  bf16x8 rbuf[2][4];                       // ref frags, 1-kt lookahead
#pragma unroll
  for (int ni = 0; ni < 4; ++ni){
    const int r = ni*16 + col;
    rbuf[0][ni] = *(const bf16x8*)(refL + r*1024 + ((quad ^ (r&7)))*16);
  }

#pragma unroll
  for (int eh = 0; eh < 2; ++eh){
#pragma unroll
    for (int kt = 0; kt < 16; ++kt){
      const int K = eh*16 + kt;            // compile-time (both loops unrolled)
      if (K + 2 < 32){                     // W prefetch, 2 kt ahead
#pragma unroll
        for (int f = 0; f < 4; ++f) wb[(K+2)&3][f] = *wptr(K+2, f);
      }
      if (K + 1 < 32){                     // ref prefetch, 1 kt ahead
        const int nk = (K+1) & 15;
#pragma unroll
        for (int ni = 0; ni < 4; ++ni){
          const int r = ni*16 + col;
          rbuf[(K+1)&1][ni] = *(const bf16x8*)(refL + r*1024 + (((nk*4 + quad) ^ (r&7)))*16);
        }
      }
#pragma unroll
      for (int f = 0; f < 4; ++f)
#pragma unroll
        for (int ni = 0; ni < 4; ++ni)     // D[s][e]: swapped operands
          acc[f>>1][f&1][ni] = __builtin_amdgcn_mfma_f32_16x16x32_bf16(
              rbuf[K&1][ni], wb[K&3][f], acc[f>>1][f&1][ni], 0, 0, 0);
    }

    // ---- epilogue for this e-half (overlaps in-flight next-pass W loads) ---
#pragma unroll
    for (int et = 0; et < 2; ++et)
#pragma unroll
      for (int mi = 0; mi < 2; ++mi){
        const int i = eh*4 + et*2 + mi;
        const int e = eh*256 + et*128 + wave*32 + mi*16 + col;
        float* orow = out + ((size_t)(b*DIM + e))*SEQ + sb + quad*4;
#pragma unroll
        for (int ni = 0; ni < 4; ++ni){    // s = sb + ni*16 + quad*4 + rg
          f32x4 v = acc[et][mi][ni];
          v.x += bb[i]; v.y += bb[i]; v.z += bb[i]; v.w += bb[i];
          *(f32x4*)(orow + ni*16) = v;     // 4 consecutive s: 16 B store
          ls[ni][0] += fast_tanh(qq[i] + v.x) * vv[i];
          ls[ni][1] += fast_tanh(qq[i] + v.y) * vv[i];
          ls[ni][2] += fast_tanh(qq[i] + v.z) * vv[i];
          ls[ni][3] += fast_tanh(qq[i] + v.w) * vv[i];
          if (eh == 0) acc[et][mi][ni] = (f32x4)0.0f;   // reset for pass 2
        }
      }
  }

  // logits: reduce over e = cols (shfl) then waves (LDS)
#pragma unroll
  for (int ni = 0; ni < 4; ++ni)
#pragma unroll
    for (int rg = 0; rg < 4; ++rg){
      float x = ls[ni][rg];
      x += __shfl_xor(x, 1); x += __shfl_xor(x, 2);
      x += __shfl_xor(x, 4); x += __shfl_xor(x, 8);
      ls[ni][rg] = x;
    }
  if (col == 0){
#pragma unroll
    for (int ni = 0; ni < 4; ++ni)
#pragma unroll
      for (int rg = 0; rg < 4; ++rg)
        lred[wave*64 + ni*16 + quad*4 + rg] = ls[ni][rg];
  }
  __syncthreads();
  if (tid < BN){
    const float s = lred[tid] + lred[64+tid] + lred[128+tid] + lred[192+tid];
    out[(size_t)NB*DIM*SEQ + b*SEQ + sb + tid] = 10.0f * fast_tanh(s);
  }
}

extern "C" void kernel_launch(void* const* d_in, const int* in_sizes, int n_in,
                              void* d_out, int out_size, void* d_ws, size_t ws_size,
                              hipStream_t stream)
{
  const float* query = (const float*)d_in[0];
  const float* ref   = (const float*)d_in[1];
  const float* Wq_w  = (const float*)d_in[2];
  const float* Wq_b  = (const float*)d_in[3];
  const float* Wr_w  = (const float*)d_in[4];
  const float* Wr_b  = (const float*)d_in[5];
  const float* value = (const float*)d_in[6];
  float* out = (float*)d_out;

  float* qws  = (float*)d_ws;                       // 64*512 fp32 = 128 KB
  u16*   wrbf = (u16*)((float*)d_ws + NB*DIM);      // 512*512 bf16 = 512 KB

  wconv_kernel<<<dim3(128), dim3(256), 0, stream>>>(Wr_w, wrbf);
  q_kernel<<<dim3(NB, 2), dim3(256), 0, stream>>>(query, Wq_w, Wq_b, qws);
  main_kernel<<<dim3(NS/BN), dim3(256), 0, stream>>>(ref, wrbf, Wr_b, value, qws, out);
}